// Round 11
// baseline (258.243 us; speedup 1.0000x reference)
//
#include <hip/hip_runtime.h>

// Problem constants
#define BB   2
#define HH   256
#define WW   256
#define HWSZ (HH * WW)        // 65536
#define CC   24
#define KSZ  7
#define KK   49               // 7*7
#define PADK 3
#define G    8                // channel groups
#define CPG  3                // channels per group
#define LSTR 24               // src halo row stride (22 padded to 24)
#define CSTR (22 * LSTR)      // channel stride in lsrc (floats)
#define LOG2E 1.44269504088896340736f

typedef __attribute__((ext_vector_type(8))) short short8;
typedef __attribute__((ext_vector_type(4))) float float4v;

// float -> bf16 bits (round-to-nearest-even) and back
__device__ __forceinline__ short f2bf(float x) {
  unsigned u = __builtin_bit_cast(unsigned, x);
  unsigned r = u + 0x7FFFu + ((u >> 16) & 1u);
  return (short)(r >> 16);
}
__device__ __forceinline__ float bf2f(short h) {
  unsigned u = ((unsigned)(unsigned short)h) << 16;
  return __builtin_bit_cast(float, u);
}

// ---------------------------------------------------------------------------
// Merged setup (one dispatch):
// blocks 0..191: split-bf16 W fragments in FRAG-MAJOR (consumer-lane) order,
//   pre-scaled by log2e. wsW[blk][lane*8+j] = W[m=lane&15][k=(lane>>4)*8+j],
//   blk = ((g*3+c)*4+mt)*2+s. Lane-contiguous 16B => conflict-free b128.
// blocks 192..703: split-bf16 B fragments (texture patch matrix), identical
//   for all 4 diffusion dispatches.
// blocks 704..1215: init out = b_td (FINAL accumulates atomically) and
//   zsum = 0 (FIRST accumulates z atomically; ws is poisoned every launch).
// ---------------------------------------------------------------------------
__global__ __launch_bounds__(256) void k_setup(
    const float* __restrict__ w_kp, const float* __restrict__ b_kp,
    const float* __restrict__ tex, short* __restrict__ wsW,
    short* __restrict__ wsB, const float* __restrict__ b_td,
    float* __restrict__ outp, float* __restrict__ zsum) {
  __shared__ float lt[3 * 324];   // 18x18 tex halo
  __shared__ int lltk[32];        // k -> tex-halo offset
  int blk = blockIdx.x;
  if (blk < 192) {
    int s = blk & 1, mt = (blk >> 1) & 3, cg = blk >> 3;   // cg = g*3+c
    for (int idx = threadIdx.x; idx < 512; idx += 256) {
      int l = idx >> 3, j = idx & 7;          // consumer lane, reg element
      int kk = mt * 16 + (l & 15);            // tap row (A row m)
      int k = (l >> 4) * 8 + j;               // K index (q*8+j)
      float v = 0.f;
      if (kk < KK && k < 28)
        v = ((k < 27) ? w_kp[((size_t)cg * KK + kk) * 27 + k]
                      : b_kp[cg * KK + kk]) * LOG2E;
      short hi = f2bf(v);
      short h = (s == 0) ? hi : f2bf(v - bf2f(hi));
      wsW[(size_t)blk * 512 + idx] = h;
    }
    return;
  }
  if (blk >= 704) {
    int i = (blk - 704) * 256 + threadIdx.x;   // 0 .. 131071 = BB*HWSZ
    outp[i] = b_td[0];
    zsum[i] = 0.f;
    return;
  }
  int tb = blk - 192;                     // 0..511
  int b = tb >> 8, tile = tb & 255;
  int y0 = (tile >> 4) * 16, x0 = (tile & 15) * 16;
  int tid = threadIdx.x, lane = tid & 63, wv = tid >> 6;
  int q = lane >> 4, col = lane & 15;

  if (tid < 32) {
    int k = tid, v;
    if (k < 27) v = (k / 9) * 324 + ((k % 9) / 3) * 18 + (k % 3);
    else if (k == 27) v = -1;     // bias slot: patch value 1.0
    else v = -2;                  // K padding: 0.0
    lltk[k] = v;
  }
  for (int idx = tid; idx < 972; idx += 256) {
    int ci = idx / 324, r = idx % 324;
    int iy = r / 18, ix = r % 18;
    int yy = y0 + iy - 1, xx = x0 + ix - 1;
    bool ok = (yy >= 0 && yy < HH && xx >= 0 && xx < WW);
    lt[idx] = ok ? tex[((size_t)b * 3 + ci) * HWSZ + yy * WW + xx] : 0.f;
  }
  __syncthreads();

  int tko[8];
#pragma unroll
  for (int j = 0; j < 8; ++j) tko[j] = lltk[q * 8 + j];
  int4* w4 = (int4*)wsB;
#pragma unroll
  for (int nt = 0; nt < 4; ++nt) {
    short8 hi, lo;
#pragma unroll
    for (int j = 0; j < 8; ++j) {
      int o = tko[j];
      float v = (o == -1) ? 1.f
                          : ((o == -2) ? 0.f : lt[o + (wv * 4 + nt) * 18 + col]);
      short h = f2bf(v);
      hi[j] = h;
      lo[j] = f2bf(v - bf2f(h));
    }
    size_t base = ((((size_t)(b * 256 + tile) * 4 + wv) * 4 + nt) * 2);
    w4[(base + 0) * 64 + lane] = __builtin_bit_cast(int4, hi);
    w4[(base + 1) * 64 + lane] = __builtin_bit_cast(int4, lo);
  }
}

// ---------------------------------------------------------------------------
// One diffusion iteration, split-bf16 MFMA logit conv, exp2 epilogue.
// R11: all 4 pixel rows (np-unrolled) per (c,mt) iteration -> A-frag LDS
// reads HALVED (the saturated-pipe saving). Both c and mt loops ROLLED
// (spill guard: exactly 1 A-pair live; tap offsets computed arithmetically
// in-loop, ~20 VALU/iter). Taps consumed inline post-MFMA (short liveness).
// z accumulated atomically into zsum by FIRST (k_zred eliminated);
// consumers compute 1/z on the fly. FINAL: atomicAdd into out (pre-init
// to b_td by k_setup).
// ---------------------------------------------------------------------------
template <bool FIRST, bool FINAL>
__global__ __launch_bounds__(256, 4) void k_diffuse_m(
    const float* __restrict__ depth, const float* __restrict__ src,
    const float* __restrict__ zsum, const float* __restrict__ w_dp,
    const float* __restrict__ b_dp, const short* __restrict__ wsW,
    const short* __restrict__ wsB, float* __restrict__ dst,
    const float* __restrict__ w_td, float* __restrict__ outp) {
  __shared__ __align__(16) short lw[24 * 512];   // 24576 B (group W frags)
  __shared__ float lsrc[CPG * CSTR];             // 6336 B
  __shared__ float ldp[FIRST ? 576 : 4];         // depth halo (FIRST only)

  int b = blockIdx.z / G, g = blockIdx.z % G, c0 = g * CPG;
  int x0 = blockIdx.x * 16, y0 = blockIdx.y * 16;
  int tile = blockIdx.y * 16 + blockIdx.x;
  int tid = threadIdx.x, lane = tid & 63, wv = tid >> 6;
  int q = lane >> 4, col = lane & 15;

  // ---- phase A: W->LDS copy (layout-preserving), depth halo ----
  {
    const int4* s4 = (const int4*)(wsW + (size_t)g * 12288);
    int4* d4 = (int4*)lw;
#pragma unroll
    for (int i = 0; i < 6; ++i) d4[tid + i * 256] = s4[tid + i * 256];
  }
  if (FIRST) {
    for (int idx = tid; idx < 576; idx += 256) {  // depth halo 24x24 @(-4,-4)
      int iy = idx / 24, ix = idx % 24;
      int yy = y0 + iy - 4, xx = x0 + ix - 4;
      bool ok = (yy >= 0 && yy < HH && xx >= 0 && xx < WW);
      ldp[idx] = ok ? depth[(size_t)b * HWSZ + yy * WW + xx] : 0.f;
    }
  }
  __syncthreads();

  // ---- phase B: src halo staging (22x22 @(-3,-3)) ----
  for (int idx = tid; idx < 484; idx += 256) {
    int iy = idx / 22, ix = idx % 22;
    int yy = y0 + iy - PADK, xx = x0 + ix - PADK;
    bool ok = (yy >= 0 && yy < HH && xx >= 0 && xx < WW);
    if (FIRST) {
#pragma unroll
      for (int c = 0; c < CPG; ++c) {
        float a = b_dp[c0 + c];
#pragma unroll
        for (int dy = 0; dy < 3; ++dy)
#pragma unroll
          for (int dx = 0; dx < 3; ++dx)
            a = fmaf(w_dp[(c0 + c) * 9 + dy * 3 + dx],
                     ldp[(iy + dy) * 24 + (ix + dx)], a);
        lsrc[c * CSTR + iy * LSTR + ix] = ok ? a : 0.f;
      }
    } else {
      float sc = 0.f;
      if (ok) sc = 1.f / zsum[b * HWSZ + yy * WW + xx];
#pragma unroll
      for (int c = 0; c < CPG; ++c)
        lsrc[c * CSTR + iy * LSTR + ix] =
            ok ? src[((size_t)b * CC + c0 + c) * HWSZ + yy * WW + xx] * sc : 0.f;
    }
  }
  __syncthreads();

  // ---- B fragments: all 4 pixel rows (precomputed, coalesced b128) ----
  const int4* wB = (const int4*)wsB + ((size_t)(b * 256 + tile) * 4 + wv) * 512;
  short8 Bh[4], Bl[4];
#pragma unroll
  for (int nt = 0; nt < 4; ++nt) {
    Bh[nt] = __builtin_bit_cast(short8, wB[(nt * 2 + 0) * 64 + lane]);
    Bl[nt] = __builtin_bit_cast(short8, wB[(nt * 2 + 1) * 64 + lane]);
  }

  const short* lA = lw + lane * 8;
  const float* base = lsrc + (wv * 4 + 3) * LSTR + col + 3;
  int q4 = q * 4;
  float accc[4] = {0.f, 0.f, 0.f, 0.f};
  float zacc[4] = {0.f, 0.f, 0.f, 0.f};
  float res[4]  = {0.f, 0.f, 0.f, 0.f};

#pragma unroll 1
  for (int c = 0; c < CPG; ++c) {
    const short* lAc = lA + c * 2048;
#pragma unroll 1
    for (int mt = 0; mt < 4; ++mt) {
      short8 Ah = *(const short8*)(lAc + mt * 1024);
      short8 Al = *(const short8*)(lAc + mt * 1024 + 512);

      // tap offsets, arithmetic (no LDS table): t/7 == (t*37)>>8 for t<=62;
      // off = t + 17*(t/7) - 75. Pad taps (t>48) clamp to 48 (e forced 0).
      int tb = mt * 16 + q4;
      int o0, o1, o2, o3;
      {
        int t0 = tb, t1 = tb + 1, t2 = tb + 2, t3 = tb + 3;
        t0 = (t0 < 48) ? t0 : 48; t1 = (t1 < 48) ? t1 : 48;
        t2 = (t2 < 48) ? t2 : 48; t3 = (t3 < 48) ? t3 : 48;
        o0 = t0 + 17 * ((t0 * 37) >> 8) - 75;
        o1 = t1 + 17 * ((t1 * 37) >> 8) - 75;
        o2 = t2 + 17 * ((t2 * 37) >> 8) - 75;
        o3 = t3 + 17 * ((t3 * 37) >> 8) - 75;
      }

      // 12 MFMAs: 3 split-bf16 x 4 pixel-row tiles
      float4v C[4];
#pragma unroll
      for (int u = 0; u < 4; ++u) {
        float4v Cu = {0.f, 0.f, 0.f, 0.f};
        Cu = __builtin_amdgcn_mfma_f32_16x16x32_bf16(Ah, Bh[u], Cu, 0, 0, 0);
        Cu = __builtin_amdgcn_mfma_f32_16x16x32_bf16(Ah, Bl[u], Cu, 0, 0, 0);
        Cu = __builtin_amdgcn_mfma_f32_16x16x32_bf16(Al, Bh[u], Cu, 0, 0, 0);
        C[u] = Cu;
      }

      if (mt < 3) {
#pragma unroll
        for (int u = 0; u < 4; ++u) {
          float e0 = __builtin_amdgcn_exp2f(C[u][0]);
          float e1 = __builtin_amdgcn_exp2f(C[u][1]);
          float e2 = __builtin_amdgcn_exp2f(C[u][2]);
          float e3 = __builtin_amdgcn_exp2f(C[u][3]);
          if (FIRST) zacc[u] += (e0 + e1) + (e2 + e3);
          float a = accc[u];
          a = fmaf(e0, base[o0 + u * LSTR], a);
          a = fmaf(e1, base[o1 + u * LSTR], a);
          a = fmaf(e2, base[o2 + u * LSTR], a);
          a = fmaf(e3, base[o3 + u * LSTR], a);
          accc[u] = a;
        }
      } else {
        // only tap row 48 (q==0, reg 0) is real in M-tile 3
#pragma unroll
        for (int u = 0; u < 4; ++u) {
          float e = (q == 0) ? __builtin_amdgcn_exp2f(C[u][0]) : 0.f;
          if (FIRST) zacc[u] += e;
          accc[u] = fmaf(e, base[o0 + u * LSTR], accc[u]);
        }
      }
    }
    // channel c complete: reduce across quads, emit
#pragma unroll
    for (int u = 0; u < 4; ++u) {
      float v = accc[u];
      v += __shfl_xor(v, 16, 64);
      v += __shfl_xor(v, 32, 64);
      if (FINAL) {
        res[u] = fmaf(w_td[c0 + c], v, res[u]);
      } else {
        int p = (y0 + wv * 4 + u) * WW + (x0 + col);
        if (lane < 16) dst[((size_t)b * CC + c0 + c) * HWSZ + p] = v;
      }
      accc[u] = 0.f;
    }
    base += CSTR;
  }

  // tail: z (FIRST, atomic) / fused to_depth atomic accumulate (FINAL)
#pragma unroll
  for (int u = 0; u < 4; ++u) {
    int p = (y0 + wv * 4 + u) * WW + (x0 + col);
    if (FIRST) {
      float z = zacc[u];
      z += __shfl_xor(z, 16, 64);
      z += __shfl_xor(z, 32, 64);
      if (lane < 16) atomicAdd((float*)&zsum[b * HWSZ + p], z);
    }
    if (FINAL) {
      if (lane < 16) {
        float rz = 1.f / zsum[b * HWSZ + p];
        atomicAdd(&outp[(size_t)b * HWSZ + p], res[u] * rz);
      }
    }
  }
}

// ---------------------------------------------------------------------------
extern "C" void kernel_launch(void* const* d_in, const int* in_sizes, int n_in,
                              void* d_out, int out_size, void* d_ws, size_t ws_size,
                              hipStream_t stream) {
  const float* depth = (const float*)d_in[0];
  const float* tex   = (const float*)d_in[1];
  const float* w_dp  = (const float*)d_in[2];
  const float* b_dp  = (const float*)d_in[3];
  const float* w_kp  = (const float*)d_in[4];
  const float* b_kp  = (const float*)d_in[5];
  const float* w_td  = (const float*)d_in[6];
  const float* b_td  = (const float*)d_in[7];
  float* out = (float*)d_out;

  // ws: bufA/bufB (12.58 MB ea) + zsum (0.5 MB) + wsW (0.2 MB) + wsB (16.8 MB)
  char* ws = (char*)d_ws;
  const size_t buf_b = (size_t)BB * CC * HWSZ * 4;
  float* bufA = (float*)ws;
  float* bufB = (float*)(ws + buf_b);
  float* zsum = (float*)(ws + 2 * buf_b);
  short* wsW  = (short*)(ws + 2 * buf_b + (size_t)BB * HWSZ * 4);
  short* wsB  = (short*)(ws + 2 * buf_b + (size_t)BB * HWSZ * 4 + 192 * 512 * 2);

  k_setup<<<dim3(192 + 512 + 512), dim3(256), 0, stream>>>(
      w_kp, b_kp, tex, wsW, wsB, b_td, out, zsum);

  dim3 grid(WW / 16, HH / 16, BB * G), blk(256);

  // iter1: fused depth_latent; emits unnormalized acc + atomic z into zsum
  k_diffuse_m<true, false><<<grid, blk, 0, stream>>>(
      depth, nullptr, zsum, w_dp, b_dp, wsW, wsB, bufB, w_td, nullptr);
  // iters 2,3: unnormalized ping-pong, 1/zsum folded into staging
  k_diffuse_m<false, false><<<grid, blk, 0, stream>>>(
      depth, bufB, zsum, w_dp, b_dp, wsW, wsB, bufA, w_td, nullptr);
  k_diffuse_m<false, false><<<grid, blk, 0, stream>>>(
      depth, bufA, zsum, w_dp, b_dp, wsW, wsB, bufB, w_td, nullptr);
  // iter4: fused to_depth, atomic accumulate into out (pre-init by k_setup)
  k_diffuse_m<false, true><<<grid, blk, 0, stream>>>(
      depth, bufB, zsum, w_dp, b_dp, wsW, wsB, nullptr, w_td, out);
}